// Round 1
// 197.194 us; speedup vs baseline: 1.2127x; 1.2127x over previous
//
#include <hip/hip_runtime.h>
#include <math.h>

#define CH 128
#define CAP 64     // bucket capacity; degrees Poisson(16), P(deg>64) ~ 3e-22
#define RSB 9      // bin range shift: 512 ids per bin
#define RS  (1 << RSB)
#define CAPB 10240 // bin capacity: mean 8192, sigma ~90 -> +22 sigma headroom
#define PB 2048    // pairs per bin-scatter block (8 per thread)

typedef __attribute__((ext_vector_type(8))) short bf16x8;
typedef __attribute__((ext_vector_type(4))) float f32x4;

__device__ __forceinline__ unsigned short f2bf(float f) {
    union { float f; unsigned u; } v; v.f = f;
    unsigned r = v.u + 0x7FFF + ((v.u >> 16) & 1);   // round-to-nearest-even
    return (unsigned short)(r >> 16);
}
__device__ __forceinline__ float bflo(unsigned u) {
    union { unsigned u; float f; } v; v.u = u << 16; return v.f;
}
__device__ __forceinline__ float bfhi(unsigned u) {
    union { unsigned u; float f; } v; v.u = u & 0xFFFF0000u; return v.f;
}
__device__ __forceinline__ unsigned pack2bf(float a, float b) {
    return (unsigned)f2bf(a) | ((unsigned)f2bf(b) << 16);
}

// ---------------------------------------------------------------------------
// Kernel 1 (mega-fused, block-specialized):
//   blocks [0, SB): PHASE-1 BINNING. The old direct bucket scatter produced
//     100MB of HBM writeback (rocprof WRITE_SIZE): every 128B col row was
//     partially dirtied by all 8 non-coherent XCD L2s -> ~8x 12.8MB masked
//     partial-line writebacks. Replaced by LDS-staged binning into 98 bins
//     per direction (512-id ranges): dense full-line 4B-entry appends, ~8MB.
//   blocks [SB, SB+GB): gemm + attention + casts (unchanged, R10-proven);
//     rides in the binning blocks' shadow (m114: pipes co-schedule at ~max).
// ---------------------------------------------------------------------------
__global__ __launch_bounds__(256) void fused_main(const float* __restrict__ x,
                                                  const float* __restrict__ attn_w,
                                                  const float* __restrict__ attn_b,
                                                  const float* __restrict__ lw,
                                                  unsigned short* __restrict__ xl,
                                                  float* __restrict__ w,
                                                  int nStrips,
                                                  const int* __restrict__ nidx,
                                                  const int* __restrict__ eidx,
                                                  int* __restrict__ binCnt,
                                                  unsigned int* __restrict__ binData,
                                                  int nnz, int nbd, int SB) {
    __shared__ unsigned short wl[128 * 136];
    __shared__ float awl[128];
    if ((int)blockIdx.x < SB) {
        // ---- LDS-staged bin scatter: pairs -> (e-keyed bins | v-keyed bins)
        int* hist = (int*)wl;          // [256] block-local per-bin counts
        int* base = ((int*)wl) + 256;  // [256] global base per bin
        int nbt = 2 * nbd;             // 196 <= 256
        for (int i = threadIdx.x; i < nbt; i += 256) hist[i] = 0;
        __syncthreads();
        int k0 = blockIdx.x * PB + threadIdx.x;
        int vv[8], ee[8], sE[8], sN[8];
#pragma unroll
        for (int u = 0; u < 8; ++u) {
            int k = k0 + u * 256;
            if (k < nnz) {
                int v = nidx[k], e = eidx[k];
                vv[u] = v; ee[u] = e;
                sE[u] = atomicAdd(&hist[e >> RSB], 1);
                sN[u] = atomicAdd(&hist[nbd + (v >> RSB)], 1);
            } else vv[u] = -1;
        }
        __syncthreads();
        for (int i = threadIdx.x; i < nbt; i += 256)
            base[i] = atomicAdd(&binCnt[i], hist[i]);
        __syncthreads();
#pragma unroll
        for (int u = 0; u < 8; ++u) {
            if (vv[u] < 0) continue;
            int bE = ee[u] >> RSB;
            int bN = nbd + (vv[u] >> RSB);
            int iE = min(base[bE] + sE[u], CAPB - 1);
            int iN = min(base[bN] + sN[u], CAPB - 1);
            binData[(size_t)bE * CAPB + iE] = ((unsigned)ee[u] << 16) | (unsigned)vv[u];
            binData[(size_t)bN * CAPB + iN] = ((unsigned)vv[u] << 16) | (unsigned)ee[u];
        }
        return;
    }
    // ---- gemm + attention part (unchanged) ----
    int tid = threadIdx.x;
    for (int i = tid; i < 2048; i += 256) {          // i = 8-element group
        float4 vlo = ((const float4*)lw)[2 * i];
        float4 vhi = ((const float4*)lw)[2 * i + 1];
        int4 dst;
        dst.x = (int)pack2bf(vlo.x, vlo.y);
        dst.y = (int)pack2bf(vlo.z, vlo.w);
        dst.z = (int)pack2bf(vhi.x, vhi.y);
        dst.w = (int)pack2bf(vhi.z, vhi.w);
        *(int4*)(wl + (i >> 4) * 136 + (i & 15) * 8) = dst;
    }
    if (tid < 128) awl[tid] = attn_w[tid];
    float ab = attn_b[0];
    __syncthreads();
    int gb = blockIdx.x - SB;
    int wid = (gb << 2) | (tid >> 6);
    int lane = tid & 63;
    int m = lane & 15, quad = lane >> 4;
    int nWaves = ((int)gridDim.x - SB) << 2;
    for (int s = wid; s < nStrips; s += nWaves) {
        int r0 = s << 4;
        const float* xr = x + (size_t)(r0 + m) * CH + quad * 8;
        float att = 0.f;
        bf16x8 a0, a1, a2, a3;
#define LOAD_FRAG(AFRAG, F)                                                   \
        {                                                                     \
            float4 lo = *(const float4*)(xr + (F) * 32);                      \
            float4 hi = *(const float4*)(xr + (F) * 32 + 4);                  \
            const float* ap = &awl[(F) * 32 + quad * 8];                      \
            att += lo.x * ap[0] + lo.y * ap[1] + lo.z * ap[2] + lo.w * ap[3]  \
                 + hi.x * ap[4] + hi.y * ap[5] + hi.z * ap[6] + hi.w * ap[7]; \
            union { int4 i; bf16x8 v; } pk;                                   \
            pk.i.x = (int)pack2bf(lo.x, lo.y);                                \
            pk.i.y = (int)pack2bf(lo.z, lo.w);                                \
            pk.i.z = (int)pack2bf(hi.x, hi.y);                                \
            pk.i.w = (int)pack2bf(hi.z, hi.w);                                \
            AFRAG = pk.v;                                                     \
        }
        LOAD_FRAG(a0, 0)
        LOAD_FRAG(a1, 1)
        LOAD_FRAG(a2, 2)
        LOAD_FRAG(a3, 3)
#undef LOAD_FRAG
        att += __shfl_xor(att, 16, 64);
        att += __shfl_xor(att, 32, 64);
        if (quad == 0) w[r0 + m] = 1.0f / (1.0f + expf(-(att + ab)));
        unsigned short* orow = xl + (size_t)(r0 + quad * 4) * CH + m;
#pragma unroll
        for (int c0 = 0; c0 < 128; c0 += 16) {
            const unsigned short* wr = wl + (c0 + m) * 136 + quad * 8;
            f32x4 acc = {0.f, 0.f, 0.f, 0.f};
            acc = __builtin_amdgcn_mfma_f32_16x16x32_bf16(a0, *(const bf16x8*)(wr), acc, 0, 0, 0);
            acc = __builtin_amdgcn_mfma_f32_16x16x32_bf16(a1, *(const bf16x8*)(wr + 32), acc, 0, 0, 0);
            acc = __builtin_amdgcn_mfma_f32_16x16x32_bf16(a2, *(const bf16x8*)(wr + 64), acc, 0, 0, 0);
            acc = __builtin_amdgcn_mfma_f32_16x16x32_bf16(a3, *(const bf16x8*)(wr + 96), acc, 0, 0, 0);
            orow[c0]            = f2bf(acc[0]);
            orow[c0 + CH]       = f2bf(acc[1]);
            orow[c0 + 2 * CH]   = f2bf(acc[2]);
            orow[c0 + 3 * CH]   = f2bf(acc[3]);
        }
    }
}

// ---------------------------------------------------------------------------
// Kernel 1b: PHASE-2 BUCKET BUILD. One block per bin => every col cache line
// has a single CU/XCD writer (no cross-XCD partial-line writeback copies),
// active 64KB slice L2-resident. Per-id counts in LDS => ZERO global count
// atomics; cnt written once with plain coalesced stores (memset also gone).
// ---------------------------------------------------------------------------
__global__ __launch_bounds__(256) void bucket_build(const int* __restrict__ binCnt,
                                                    const unsigned int* __restrict__ binData,
                                                    int* __restrict__ cntE,
                                                    unsigned short* __restrict__ colE,
                                                    int* __restrict__ cntN,
                                                    unsigned short* __restrict__ colN,
                                                    int nbd, int N) {
    __shared__ int cl[RS];
    int b = blockIdx.x;                  // [0, 2*nbd)
    int isN = b >= nbd;
    int bl = isN ? b - nbd : b;
    int idBase = bl << RSB;
    int* cnt = isN ? cntN : cntE;
    unsigned short* col = isN ? colN : colE;
    for (int i = threadIdx.x; i < RS; i += 256) cl[i] = 0;
    __syncthreads();
    int n = min(binCnt[b], CAPB);
    const unsigned int* src = binData + (size_t)b * CAPB;
    for (int i = threadIdx.x; i < n; i += 256) {
        unsigned int entry = src[i];
        int id  = (int)(entry >> 16);
        int val = (int)(entry & 0xFFFFu);
        int r = atomicAdd(&cl[id - idBase], 1);
        col[(size_t)id * CAP + min(r, CAP - 1)] = (unsigned short)val;
    }
    __syncthreads();
    for (int i = threadIdx.x; i < RS; i += 256) {
        int gid = idBase + i;
        if (gid < N) cnt[gid] = cl[i];
    }
}

// ---------------------------------------------------------------------------
// Kernel 2: edge pull — ef_bf[e,:] = bf16( (1/deg) * sum_{v in e} xl_bf[v,:] )
// [R8/R10-proven, untouched this round for clean attribution]
// ---------------------------------------------------------------------------
__global__ __launch_bounds__(256) void edge_pull(const int* __restrict__ cntE,
                                                 const unsigned short* __restrict__ colE,
                                                 const unsigned short* __restrict__ xl,
                                                 unsigned short* __restrict__ ef, int M) {
    int e = (blockIdx.x << 2) | (threadIdx.x >> 6);
    if (e >= M) return;
    int lane = threadIdx.x & 63;
    int deg = cntE[e];
    const unsigned short* col = colE + (size_t)e * CAP;
    float2 a0 = {0.f, 0.f}, a1 = {0.f, 0.f}, a2 = {0.f, 0.f}, a3 = {0.f, 0.f};
    int j = 0;
    for (; j + 3 < deg; j += 4) {
        int v0 = col[j], v1 = col[j + 1], v2 = col[j + 2], v3 = col[j + 3];
        unsigned u0 = *(const unsigned*)(xl + (size_t)v0 * CH + 2 * lane);
        unsigned u1 = *(const unsigned*)(xl + (size_t)v1 * CH + 2 * lane);
        unsigned u2 = *(const unsigned*)(xl + (size_t)v2 * CH + 2 * lane);
        unsigned u3 = *(const unsigned*)(xl + (size_t)v3 * CH + 2 * lane);
        a0.x += bflo(u0); a0.y += bfhi(u0);
        a1.x += bflo(u1); a1.y += bfhi(u1);
        a2.x += bflo(u2); a2.y += bfhi(u2);
        a3.x += bflo(u3); a3.y += bfhi(u3);
    }
    for (; j < deg; ++j) {
        unsigned u0 = *(const unsigned*)(xl + (size_t)col[j] * CH + 2 * lane);
        a0.x += bflo(u0); a0.y += bfhi(u0);
    }
    a0.x += a1.x + a2.x + a3.x;
    a0.y += a1.y + a2.y + a3.y;
    float binv = deg > 0 ? 1.0f / (float)deg : 0.0f;
    *(unsigned*)(ef + (size_t)e * CH + 2 * lane) = pack2bf(a0.x * binv, a0.y * binv);
}

// ---------------------------------------------------------------------------
// Kernel 3: node pull — out[v,:] = Dinv[v] * sum_{e at v} ef_bf[e,:] + bias
// [R8/R10-proven, untouched this round]
// ---------------------------------------------------------------------------
__global__ __launch_bounds__(256) void node_pull(const int* __restrict__ cntN,
                                                 const unsigned short* __restrict__ colN,
                                                 const unsigned short* __restrict__ ef,
                                                 const float* __restrict__ w,
                                                 const float* __restrict__ bias,
                                                 float* __restrict__ out, int N) {
    int v = (blockIdx.x << 2) | (threadIdx.x >> 6);
    if (v >= N) return;
    int lane = threadIdx.x & 63;
    int deg = cntN[v];
    const unsigned short* col = colN + (size_t)v * CAP;
    float2 a0 = {0.f, 0.f}, a1 = {0.f, 0.f}, a2 = {0.f, 0.f}, a3 = {0.f, 0.f};
    float ds = 0.f;
    int j = 0;
    for (; j + 3 < deg; j += 4) {
        int e0 = col[j], e1 = col[j + 1], e2 = col[j + 2], e3 = col[j + 3];
        unsigned u0 = *(const unsigned*)(ef + (size_t)e0 * CH + 2 * lane);
        unsigned u1 = *(const unsigned*)(ef + (size_t)e1 * CH + 2 * lane);
        unsigned u2 = *(const unsigned*)(ef + (size_t)e2 * CH + 2 * lane);
        unsigned u3 = *(const unsigned*)(ef + (size_t)e3 * CH + 2 * lane);
        ds += w[e0] + w[e1] + w[e2] + w[e3];
        a0.x += bflo(u0); a0.y += bfhi(u0);
        a1.x += bflo(u1); a1.y += bfhi(u1);
        a2.x += bflo(u2); a2.y += bfhi(u2);
        a3.x += bflo(u3); a3.y += bfhi(u3);
    }
    for (; j < deg; ++j) {
        int e0 = col[j];
        unsigned u0 = *(const unsigned*)(ef + (size_t)e0 * CH + 2 * lane);
        ds += w[e0];
        a0.x += bflo(u0); a0.y += bfhi(u0);
    }
    a0.x += a1.x + a2.x + a3.x;
    a0.y += a1.y + a2.y + a3.y;
    float dinv = ds > 0.f ? 1.0f / ds : 0.0f;
    float2 bi = *(const float2*)(bias + 2 * lane);
    float2 o = {a0.x * dinv + bi.x, a0.y * dinv + bi.y};
    *(float2*)(out + (size_t)v * CH + 2 * lane) = o;
}

extern "C" void kernel_launch(void* const* d_in, const int* in_sizes, int n_in,
                              void* d_out, int out_size, void* d_ws, size_t ws_size,
                              hipStream_t stream) {
    const float* x      = (const float*)d_in[0];
    const int*   hei    = (const int*)d_in[1];
    const float* attn_w = (const float*)d_in[2];
    const float* attn_b = (const float*)d_in[3];
    const float* lin_w  = (const float*)d_in[4];
    const float* bias   = (const float*)d_in[5];
    float* out = (float*)d_out;

    const int N   = in_sizes[0] / CH;   // 50000 (== M here)
    const int nnz = in_sizes[1] / 2;    // 800000
    const int* nidx = hei;              // row 0: node ids
    const int* eidx = hei + nnz;        // row 1: hyperedge ids

    // workspace layout (total unchanged vs previous round: 26.2MB)
    unsigned short* S    = (unsigned short*)d_ws;          // N*CH ushorts (efbf)
    float*          w    = (float*)(S + (size_t)N * CH);   // N floats
    int*            cntE = (int*)(w + N);                  // N
    int*            cntN = cntE + N;                       // N
    unsigned short* colE = (unsigned short*)(cntN + N);    // N*CAP ushorts
    unsigned short* colN = colE + (size_t)N * CAP;         // N*CAP ushorts

    // bins alias the efbf region (dead until edge_pull): binData 8.03MB < 12MB,
    // binCnt parked at S+12MB (within the 12.8MB S region, past binData).
    unsigned int* binData = (unsigned int*)S;
    int*          binCnt  = (int*)((char*)d_ws + (size_t)12 * 1024 * 1024);
    unsigned short* efbf = S;
    unsigned short* xlbf = (unsigned short*)out;   // bf16 xl in d_out

    int nbd = (N + RS - 1) >> RSB;         // 98 bins per direction
    hipMemsetAsync(binCnt, 0, (size_t)2 * nbd * sizeof(int), stream);

    int SB = (nnz + PB - 1) / PB;          // 391 binning blocks
    int nStrips = N / 16;                  // 3125
    int GB = (nStrips + 3) / 4;            // 782 gemm blocks
    fused_main<<<SB + GB, 256, 0, stream>>>(x, attn_w, attn_b, lin_w, xlbf, w,
                                            nStrips, nidx, eidx, binCnt, binData,
                                            nnz, nbd, SB);

    bucket_build<<<2 * nbd, 256, 0, stream>>>(binCnt, binData, cntE, colE, cntN, colN, nbd, N);
    edge_pull<<<(N + 3) / 4, 256, 0, stream>>>(cntE, colE, xlbf, efbf, N);
    node_pull<<<(N + 3) / 4, 256, 0, stream>>>(cntN, colN, efbf, w, bias, out, N);
}

// Round 2
// 180.302 us; speedup vs baseline: 1.3264x; 1.0937x over previous
//
#include <hip/hip_runtime.h>
#include <math.h>

#define CH 128
#define CAP 64     // per-id bucket capacity; degrees Poisson(16), P(deg>64) ~ 3e-22
#define RSB 9      // coarse bin shift: 512 ids per bin
#define RS  (1 << RSB)
#define CAPB 10240 // coarse bin capacity: mean 8163, sigma ~90 -> +23 sigma headroom
#define PB 2048    // pairs per bin-scatter block (8 per thread)
#define SUB 8      // agg sub-blocks per coarse bin (64 ids each)
#define IDS 64     // ids per agg block

typedef __attribute__((ext_vector_type(8))) short bf16x8;
typedef __attribute__((ext_vector_type(4))) float f32x4;

__device__ __forceinline__ unsigned short f2bf(float f) {
    union { float f; unsigned u; } v; v.f = f;
    unsigned r = v.u + 0x7FFF + ((v.u >> 16) & 1);   // round-to-nearest-even
    return (unsigned short)(r >> 16);
}
__device__ __forceinline__ float bflo(unsigned u) {
    union { unsigned u; float f; } v; v.u = u << 16; return v.f;
}
__device__ __forceinline__ float bfhi(unsigned u) {
    union { unsigned u; float f; } v; v.u = u & 0xFFFF0000u; return v.f;
}
__device__ __forceinline__ unsigned pack2bf(float a, float b) {
    return (unsigned)f2bf(a) | ((unsigned)f2bf(b) << 16);
}

// ---------------------------------------------------------------------------
// Kernel 1 (mega-fused, block-specialized) [R1-proven, unchanged]:
//   blocks [0, SB): LDS-staged binning into 98 coarse bins per direction
//     (512-id ranges). Block-level reservation gives contiguous ~21-entry
//     runs per (block,bin) -> dense full-line appends, no cross-XCD
//     partial-line writeback (the R0 100MB WRITE_SIZE pathology).
//   blocks [SB, SB+GB): gemm + attention + casts; rides in the binning
//     blocks' shadow (m114: pipes co-schedule at ~max).
// ---------------------------------------------------------------------------
__global__ __launch_bounds__(256) void fused_main(const float* __restrict__ x,
                                                  const float* __restrict__ attn_w,
                                                  const float* __restrict__ attn_b,
                                                  const float* __restrict__ lw,
                                                  unsigned short* __restrict__ xl,
                                                  float* __restrict__ w,
                                                  int nStrips,
                                                  const int* __restrict__ nidx,
                                                  const int* __restrict__ eidx,
                                                  int* __restrict__ binCnt,
                                                  unsigned int* __restrict__ binData,
                                                  int nnz, int nbd, int SB) {
    __shared__ unsigned short wl[128 * 136];
    __shared__ float awl[128];
    if ((int)blockIdx.x < SB) {
        // ---- LDS-staged bin scatter: pairs -> (e-keyed bins | v-keyed bins)
        int* hist = (int*)wl;          // [2*nbd] block-local per-bin counts
        int* base = ((int*)wl) + 256;  // [2*nbd] global base per bin
        int nbt = 2 * nbd;             // 196 <= 256
        for (int i = threadIdx.x; i < nbt; i += 256) hist[i] = 0;
        __syncthreads();
        int k0 = blockIdx.x * PB + threadIdx.x;
        int vv[8], ee[8], sE[8], sN[8];
#pragma unroll
        for (int u = 0; u < 8; ++u) {
            int k = k0 + u * 256;
            if (k < nnz) {
                int v = nidx[k], e = eidx[k];
                vv[u] = v; ee[u] = e;
                sE[u] = atomicAdd(&hist[e >> RSB], 1);
                sN[u] = atomicAdd(&hist[nbd + (v >> RSB)], 1);
            } else vv[u] = -1;
        }
        __syncthreads();
        for (int i = threadIdx.x; i < nbt; i += 256)
            if (hist[i]) base[i] = atomicAdd(&binCnt[i], hist[i]);
        __syncthreads();
#pragma unroll
        for (int u = 0; u < 8; ++u) {
            if (vv[u] < 0) continue;
            int bE = ee[u] >> RSB;
            int bN = nbd + (vv[u] >> RSB);
            int iE = min(base[bE] + sE[u], CAPB - 1);
            int iN = min(base[bN] + sN[u], CAPB - 1);
            binData[(size_t)bE * CAPB + iE] = ((unsigned)ee[u] << 16) | (unsigned)vv[u];
            binData[(size_t)bN * CAPB + iN] = ((unsigned)vv[u] << 16) | (unsigned)ee[u];
        }
        return;
    }
    // ---- gemm + attention part (unchanged) ----
    int tid = threadIdx.x;
    for (int i = tid; i < 2048; i += 256) {          // i = 8-element group
        float4 vlo = ((const float4*)lw)[2 * i];
        float4 vhi = ((const float4*)lw)[2 * i + 1];
        int4 dst;
        dst.x = (int)pack2bf(vlo.x, vlo.y);
        dst.y = (int)pack2bf(vlo.z, vlo.w);
        dst.z = (int)pack2bf(vhi.x, vhi.y);
        dst.w = (int)pack2bf(vhi.z, vhi.w);
        *(int4*)(wl + (i >> 4) * 136 + (i & 15) * 8) = dst;
    }
    if (tid < 128) awl[tid] = attn_w[tid];
    float ab = attn_b[0];
    __syncthreads();
    int gb = blockIdx.x - SB;
    int wid = (gb << 2) | (tid >> 6);
    int lane = tid & 63;
    int m = lane & 15, quad = lane >> 4;
    int nWaves = ((int)gridDim.x - SB) << 2;
    for (int s = wid; s < nStrips; s += nWaves) {
        int r0 = s << 4;
        const float* xr = x + (size_t)(r0 + m) * CH + quad * 8;
        float att = 0.f;
        bf16x8 a0, a1, a2, a3;
#define LOAD_FRAG(AFRAG, F)                                                   \
        {                                                                     \
            float4 lo = *(const float4*)(xr + (F) * 32);                      \
            float4 hi = *(const float4*)(xr + (F) * 32 + 4);                  \
            const float* ap = &awl[(F) * 32 + quad * 8];                      \
            att += lo.x * ap[0] + lo.y * ap[1] + lo.z * ap[2] + lo.w * ap[3]  \
                 + hi.x * ap[4] + hi.y * ap[5] + hi.z * ap[6] + hi.w * ap[7]; \
            union { int4 i; bf16x8 v; } pk;                                   \
            pk.i.x = (int)pack2bf(lo.x, lo.y);                                \
            pk.i.y = (int)pack2bf(lo.z, lo.w);                                \
            pk.i.z = (int)pack2bf(hi.x, hi.y);                                \
            pk.i.w = (int)pack2bf(hi.z, hi.w);                                \
            AFRAG = pk.v;                                                     \
        }
        LOAD_FRAG(a0, 0)
        LOAD_FRAG(a1, 1)
        LOAD_FRAG(a2, 2)
        LOAD_FRAG(a3, 3)
#undef LOAD_FRAG
        att += __shfl_xor(att, 16, 64);
        att += __shfl_xor(att, 32, 64);
        if (quad == 0) w[r0 + m] = 1.0f / (1.0f + expf(-(att + ab)));
        unsigned short* orow = xl + (size_t)(r0 + quad * 4) * CH + m;
#pragma unroll
        for (int c0 = 0; c0 < 128; c0 += 16) {
            const unsigned short* wr = wl + (c0 + m) * 136 + quad * 8;
            f32x4 acc = {0.f, 0.f, 0.f, 0.f};
            acc = __builtin_amdgcn_mfma_f32_16x16x32_bf16(a0, *(const bf16x8*)(wr), acc, 0, 0, 0);
            acc = __builtin_amdgcn_mfma_f32_16x16x32_bf16(a1, *(const bf16x8*)(wr + 32), acc, 0, 0, 0);
            acc = __builtin_amdgcn_mfma_f32_16x16x32_bf16(a2, *(const bf16x8*)(wr + 64), acc, 0, 0, 0);
            acc = __builtin_amdgcn_mfma_f32_16x16x32_bf16(a3, *(const bf16x8*)(wr + 96), acc, 0, 0, 0);
            orow[c0]            = f2bf(acc[0]);
            orow[c0 + CH]       = f2bf(acc[1]);
            orow[c0 + 2 * CH]   = f2bf(acc[2]);
            orow[c0 + 3 * CH]   = f2bf(acc[3]);
        }
    }
}

// ---------------------------------------------------------------------------
// Kernel 2: edge agg — bucket_build FOLDED IN. Each block owns a 64-id
// sub-range of one coarse bin: scans the bin's binData slice (coalesced,
// L2-resident; 8x redundancy ~ cheap), builds per-id member lists in 8KB
// LDS, then aggregates with member ids from LDS broadcast reads.
// Kills: bucket_build dispatch, 13.2MB col/cnt writes + 13.2MB re-reads,
// the 400KB cnt memset, one kernel-boundary sync.
//   ef[e,:] = bf16( (1/deg) * sum_{v in e} xl_bf[v,:] )
// ---------------------------------------------------------------------------
__global__ __launch_bounds__(512) void edge_agg(const int* __restrict__ binCnt,
                                                const unsigned int* __restrict__ binData,
                                                const unsigned short* __restrict__ xl,
                                                unsigned short* __restrict__ ef, int M) {
    __shared__ unsigned short bucket[IDS * CAP];   // 8KB
    __shared__ int cl[IDS];
    int cb = blockIdx.x >> 3;            // coarse bin
    int sr = blockIdx.x & (SUB - 1);     // sub-range within bin
    int idBase = (cb << RSB) + (sr << 6);
    for (int i = threadIdx.x; i < IDS; i += 512) cl[i] = 0;
    __syncthreads();
    int n = min(binCnt[cb], CAPB);
    const unsigned int* src = binData + (size_t)cb * CAPB;
    for (int i = threadIdx.x; i < n; i += 512) {
        unsigned int entry = src[i];
        int lid = (int)(entry >> 16) - idBase;
        if ((unsigned)lid < IDS) {
            int r = atomicAdd(&cl[lid], 1);
            bucket[(lid << 6) + min(r, CAP - 1)] = (unsigned short)(entry & 0xFFFFu);
        }
    }
    __syncthreads();
    int wid = threadIdx.x >> 6, lane = threadIdx.x & 63;
    for (int li = wid; li < IDS; li += 8) {
        int gid = idBase + li;
        if (gid >= M) break;
        int deg = cl[li];
        int dl = min(deg, CAP);
        const unsigned short* col = bucket + (li << 6);
        float2 a0 = {0.f, 0.f}, a1 = {0.f, 0.f}, a2 = {0.f, 0.f}, a3 = {0.f, 0.f};
        int j = 0;
        for (; j + 3 < dl; j += 4) {
            int v0 = col[j], v1 = col[j + 1], v2 = col[j + 2], v3 = col[j + 3];
            unsigned u0 = *(const unsigned*)(xl + (size_t)v0 * CH + 2 * lane);
            unsigned u1 = *(const unsigned*)(xl + (size_t)v1 * CH + 2 * lane);
            unsigned u2 = *(const unsigned*)(xl + (size_t)v2 * CH + 2 * lane);
            unsigned u3 = *(const unsigned*)(xl + (size_t)v3 * CH + 2 * lane);
            a0.x += bflo(u0); a0.y += bfhi(u0);
            a1.x += bflo(u1); a1.y += bfhi(u1);
            a2.x += bflo(u2); a2.y += bfhi(u2);
            a3.x += bflo(u3); a3.y += bfhi(u3);
        }
        for (; j < dl; ++j) {
            unsigned u0 = *(const unsigned*)(xl + (size_t)col[j] * CH + 2 * lane);
            a0.x += bflo(u0); a0.y += bfhi(u0);
        }
        a0.x += a1.x + a2.x + a3.x;
        a0.y += a1.y + a2.y + a3.y;
        float binv = deg > 0 ? 1.0f / (float)deg : 0.0f;
        *(unsigned*)(ef + (size_t)gid * CH + 2 * lane) = pack2bf(a0.x * binv, a0.y * binv);
    }
}

// ---------------------------------------------------------------------------
// Kernel 3: node agg — same folded structure for the N direction.
//   out[v,:] = (1/sum_{e at v} w[e]) * sum_{e at v} ef_bf[e,:] + bias
// ---------------------------------------------------------------------------
__global__ __launch_bounds__(512) void node_agg(const int* __restrict__ binCnt,
                                                const unsigned int* __restrict__ binData,
                                                const unsigned short* __restrict__ ef,
                                                const float* __restrict__ w,
                                                const float* __restrict__ bias,
                                                float* __restrict__ out, int N) {
    __shared__ unsigned short bucket[IDS * CAP];
    __shared__ int cl[IDS];
    int cb = blockIdx.x >> 3;
    int sr = blockIdx.x & (SUB - 1);
    int idBase = (cb << RSB) + (sr << 6);
    for (int i = threadIdx.x; i < IDS; i += 512) cl[i] = 0;
    __syncthreads();
    int n = min(binCnt[cb], CAPB);
    const unsigned int* src = binData + (size_t)cb * CAPB;
    for (int i = threadIdx.x; i < n; i += 512) {
        unsigned int entry = src[i];
        int lid = (int)(entry >> 16) - idBase;
        if ((unsigned)lid < IDS) {
            int r = atomicAdd(&cl[lid], 1);
            bucket[(lid << 6) + min(r, CAP - 1)] = (unsigned short)(entry & 0xFFFFu);
        }
    }
    __syncthreads();
    int wid = threadIdx.x >> 6, lane = threadIdx.x & 63;
    for (int li = wid; li < IDS; li += 8) {
        int gid = idBase + li;
        if (gid >= N) break;
        int deg = cl[li];
        int dl = min(deg, CAP);
        const unsigned short* col = bucket + (li << 6);
        float2 a0 = {0.f, 0.f}, a1 = {0.f, 0.f}, a2 = {0.f, 0.f}, a3 = {0.f, 0.f};
        float ds = 0.f;
        int j = 0;
        for (; j + 3 < dl; j += 4) {
            int e0 = col[j], e1 = col[j + 1], e2 = col[j + 2], e3 = col[j + 3];
            unsigned u0 = *(const unsigned*)(ef + (size_t)e0 * CH + 2 * lane);
            unsigned u1 = *(const unsigned*)(ef + (size_t)e1 * CH + 2 * lane);
            unsigned u2 = *(const unsigned*)(ef + (size_t)e2 * CH + 2 * lane);
            unsigned u3 = *(const unsigned*)(ef + (size_t)e3 * CH + 2 * lane);
            ds += w[e0] + w[e1] + w[e2] + w[e3];
            a0.x += bflo(u0); a0.y += bfhi(u0);
            a1.x += bflo(u1); a1.y += bfhi(u1);
            a2.x += bflo(u2); a2.y += bfhi(u2);
            a3.x += bflo(u3); a3.y += bfhi(u3);
        }
        for (; j < dl; ++j) {
            int e0 = col[j];
            unsigned u0 = *(const unsigned*)(ef + (size_t)e0 * CH + 2 * lane);
            ds += w[e0];
            a0.x += bflo(u0); a0.y += bfhi(u0);
        }
        a0.x += a1.x + a2.x + a3.x;
        a0.y += a1.y + a2.y + a3.y;
        float dinv = ds > 0.f ? 1.0f / ds : 0.0f;
        float2 bi = *(const float2*)(bias + 2 * lane);
        float2 o = {a0.x * dinv + bi.x, a0.y * dinv + bi.y};
        *(float2*)(out + (size_t)gid * CH + 2 * lane) = o;
    }
}

extern "C" void kernel_launch(void* const* d_in, const int* in_sizes, int n_in,
                              void* d_out, int out_size, void* d_ws, size_t ws_size,
                              hipStream_t stream) {
    const float* x      = (const float*)d_in[0];
    const int*   hei    = (const int*)d_in[1];
    const float* attn_w = (const float*)d_in[2];
    const float* attn_b = (const float*)d_in[3];
    const float* lin_w  = (const float*)d_in[4];
    const float* bias   = (const float*)d_in[5];
    float* out = (float*)d_out;

    const int N   = in_sizes[0] / CH;   // 50000 (== M here)
    const int nnz = in_sizes[1] / 2;    // 800000
    const int* nidx = hei;              // row 0: node ids
    const int* eidx = hei + nnz;        // row 1: hyperedge ids

    // workspace layout (~21.2MB; col/cnt arrays eliminated this round):
    //   ef      : N*CH ushorts (12.8MB)
    //   w       : N floats (0.2MB)
    //   binData : 2*nbd*CAPB uints (8.03MB) — own region, NO aliasing with ef
    //             (node_agg reads N-bins after edge_agg wrote ef)
    //   binCnt  : 2*nbd ints
    unsigned short* efbf = (unsigned short*)d_ws;
    float*          w    = (float*)(efbf + (size_t)N * CH);
    unsigned int*   binData = (unsigned int*)(w + N);
    int nbd = (N + RS - 1) >> RSB;         // 98 bins per direction
    int*            binCnt  = (int*)(binData + (size_t)2 * nbd * CAPB);

    unsigned short* xlbf = (unsigned short*)out;   // bf16 xl in d_out (dead after edge_agg)

    hipMemsetAsync(binCnt, 0, (size_t)2 * nbd * sizeof(int), stream);

    int SB = (nnz + PB - 1) / PB;          // 391 binning blocks
    int nStrips = N / 16;                  // 3125
    int GB = (nStrips + 3) / 4;            // 782 gemm blocks
    fused_main<<<SB + GB, 256, 0, stream>>>(x, attn_w, attn_b, lin_w, xlbf, w,
                                            nStrips, nidx, eidx, binCnt, binData,
                                            nnz, nbd, SB);

    edge_agg<<<nbd * SUB, 512, 0, stream>>>(binCnt, binData, xlbf, efbf, N);
    node_agg<<<nbd * SUB, 512, 0, stream>>>(binCnt + nbd,
                                            binData + (size_t)nbd * CAPB,
                                            efbf, w, bias, out, N);
}

// Round 3
// 176.081 us; speedup vs baseline: 1.3582x; 1.0240x over previous
//
#include <hip/hip_runtime.h>
#include <math.h>

#define CH 128
#define CAP 64     // per-id bucket capacity; degrees Poisson(16), P(deg>64) ~ 3e-22
#define RSB 9      // coarse bin shift: 512 ids per bin
#define RS  (1 << RSB)
#define CAPB 10240 // coarse bin capacity: mean 8163, sigma ~90 -> +23 sigma headroom
#define PB 2048    // pairs per bin-scatter block (8 per thread)
#define SUB 16     // agg sub-blocks per coarse bin (32 ids each)
#define IDS 32     // ids per agg block

typedef __attribute__((ext_vector_type(8))) short bf16x8;
typedef __attribute__((ext_vector_type(4))) float f32x4;

__device__ __forceinline__ unsigned short f2bf(float f) {
    union { float f; unsigned u; } v; v.f = f;
    unsigned r = v.u + 0x7FFF + ((v.u >> 16) & 1);   // round-to-nearest-even
    return (unsigned short)(r >> 16);
}
__device__ __forceinline__ float bflo(unsigned u) {
    union { unsigned u; float f; } v; v.u = u << 16; return v.f;
}
__device__ __forceinline__ float bfhi(unsigned u) {
    union { unsigned u; float f; } v; v.u = u & 0xFFFF0000u; return v.f;
}
__device__ __forceinline__ unsigned pack2bf(float a, float b) {
    return (unsigned)f2bf(a) | ((unsigned)f2bf(b) << 16);
}

// ---------------------------------------------------------------------------
// Kernel 1 (mega-fused, block-specialized) [R1/R2-proven, unchanged]:
//   blocks [0, SB): LDS-staged binning into 98 coarse bins per direction.
//   blocks [SB, SB+GB): gemm + attention + casts, rides in binning's shadow.
// ---------------------------------------------------------------------------
__global__ __launch_bounds__(256) void fused_main(const float* __restrict__ x,
                                                  const float* __restrict__ attn_w,
                                                  const float* __restrict__ attn_b,
                                                  const float* __restrict__ lw,
                                                  unsigned short* __restrict__ xl,
                                                  float* __restrict__ w,
                                                  int nStrips,
                                                  const int* __restrict__ nidx,
                                                  const int* __restrict__ eidx,
                                                  int* __restrict__ binCnt,
                                                  unsigned int* __restrict__ binData,
                                                  int nnz, int nbd, int SB) {
    __shared__ unsigned short wl[128 * 136];
    __shared__ float awl[128];
    if ((int)blockIdx.x < SB) {
        int* hist = (int*)wl;          // [2*nbd] block-local per-bin counts
        int* base = ((int*)wl) + 256;  // [2*nbd] global base per bin
        int nbt = 2 * nbd;             // 196 <= 256
        for (int i = threadIdx.x; i < nbt; i += 256) hist[i] = 0;
        __syncthreads();
        int k0 = blockIdx.x * PB + threadIdx.x;
        int vv[8], ee[8], sE[8], sN[8];
#pragma unroll
        for (int u = 0; u < 8; ++u) {
            int k = k0 + u * 256;
            if (k < nnz) {
                int v = nidx[k], e = eidx[k];
                vv[u] = v; ee[u] = e;
                sE[u] = atomicAdd(&hist[e >> RSB], 1);
                sN[u] = atomicAdd(&hist[nbd + (v >> RSB)], 1);
            } else vv[u] = -1;
        }
        __syncthreads();
        for (int i = threadIdx.x; i < nbt; i += 256)
            if (hist[i]) base[i] = atomicAdd(&binCnt[i], hist[i]);
        __syncthreads();
#pragma unroll
        for (int u = 0; u < 8; ++u) {
            if (vv[u] < 0) continue;
            int bE = ee[u] >> RSB;
            int bN = nbd + (vv[u] >> RSB);
            int iE = min(base[bE] + sE[u], CAPB - 1);
            int iN = min(base[bN] + sN[u], CAPB - 1);
            binData[(size_t)bE * CAPB + iE] = ((unsigned)ee[u] << 16) | (unsigned)vv[u];
            binData[(size_t)bN * CAPB + iN] = ((unsigned)vv[u] << 16) | (unsigned)ee[u];
        }
        return;
    }
    // ---- gemm + attention part (unchanged) ----
    int tid = threadIdx.x;
    for (int i = tid; i < 2048; i += 256) {          // i = 8-element group
        float4 vlo = ((const float4*)lw)[2 * i];
        float4 vhi = ((const float4*)lw)[2 * i + 1];
        int4 dst;
        dst.x = (int)pack2bf(vlo.x, vlo.y);
        dst.y = (int)pack2bf(vlo.z, vlo.w);
        dst.z = (int)pack2bf(vhi.x, vhi.y);
        dst.w = (int)pack2bf(vhi.z, vhi.w);
        *(int4*)(wl + (i >> 4) * 136 + (i & 15) * 8) = dst;
    }
    if (tid < 128) awl[tid] = attn_w[tid];
    float ab = attn_b[0];
    __syncthreads();
    int gb = blockIdx.x - SB;
    int wid = (gb << 2) | (tid >> 6);
    int lane = tid & 63;
    int m = lane & 15, quad = lane >> 4;
    int nWaves = ((int)gridDim.x - SB) << 2;
    for (int s = wid; s < nStrips; s += nWaves) {
        int r0 = s << 4;
        const float* xr = x + (size_t)(r0 + m) * CH + quad * 8;
        float att = 0.f;
        bf16x8 a0, a1, a2, a3;
#define LOAD_FRAG(AFRAG, F)                                                   \
        {                                                                     \
            float4 lo = *(const float4*)(xr + (F) * 32);                      \
            float4 hi = *(const float4*)(xr + (F) * 32 + 4);                  \
            const float* ap = &awl[(F) * 32 + quad * 8];                      \
            att += lo.x * ap[0] + lo.y * ap[1] + lo.z * ap[2] + lo.w * ap[3]  \
                 + hi.x * ap[4] + hi.y * ap[5] + hi.z * ap[6] + hi.w * ap[7]; \
            union { int4 i; bf16x8 v; } pk;                                   \
            pk.i.x = (int)pack2bf(lo.x, lo.y);                                \
            pk.i.y = (int)pack2bf(lo.z, lo.w);                                \
            pk.i.z = (int)pack2bf(hi.x, hi.y);                                \
            pk.i.w = (int)pack2bf(hi.z, hi.w);                                \
            AFRAG = pk.v;                                                     \
        }
        LOAD_FRAG(a0, 0)
        LOAD_FRAG(a1, 1)
        LOAD_FRAG(a2, 2)
        LOAD_FRAG(a3, 3)
#undef LOAD_FRAG
        att += __shfl_xor(att, 16, 64);
        att += __shfl_xor(att, 32, 64);
        if (quad == 0) w[r0 + m] = 1.0f / (1.0f + expf(-(att + ab)));
        unsigned short* orow = xl + (size_t)(r0 + quad * 4) * CH + m;
#pragma unroll
        for (int c0 = 0; c0 < 128; c0 += 16) {
            const unsigned short* wr = wl + (c0 + m) * 136 + quad * 8;
            f32x4 acc = {0.f, 0.f, 0.f, 0.f};
            acc = __builtin_amdgcn_mfma_f32_16x16x32_bf16(a0, *(const bf16x8*)(wr), acc, 0, 0, 0);
            acc = __builtin_amdgcn_mfma_f32_16x16x32_bf16(a1, *(const bf16x8*)(wr + 32), acc, 0, 0, 0);
            acc = __builtin_amdgcn_mfma_f32_16x16x32_bf16(a2, *(const bf16x8*)(wr + 64), acc, 0, 0, 0);
            acc = __builtin_amdgcn_mfma_f32_16x16x32_bf16(a3, *(const bf16x8*)(wr + 96), acc, 0, 0, 0);
            orow[c0]            = f2bf(acc[0]);
            orow[c0 + CH]       = f2bf(acc[1]);
            orow[c0 + 2 * CH]   = f2bf(acc[2]);
            orow[c0 + 3 * CH]   = f2bf(acc[3]);
        }
    }
}

// ---------------------------------------------------------------------------
// Kernel 2: edge agg, latency-optimized rebuild of R2's folded kernel.
//   R2 was latency-bound (~44us vs ~12us BW cost): 4 outstanding full-wave
//   dword loads/wave, ~6 waves/SIMD. This version:
//   - half-wave pair layout: lanes 0-31 read member 2j, lanes 32-63 member
//     2j+1, dwordx2/lane (4 ch) -> half the VMEM instrs, 2x rows in flight;
//     one shfl_xor(32) combine at the end.
//   - IDS 32 / SUB 16 -> 1568 blocks x 8 waves, __launch_bounds__(512,8)
//     pins VGPR<=64 -> 8 waves/SIMD (HW cap).
//   - unroll 4 pairs -> 8 rows outstanding per wave.
// ---------------------------------------------------------------------------
__global__ __launch_bounds__(512, 8) void edge_agg(const int* __restrict__ binCnt,
                                                   const unsigned int* __restrict__ binData,
                                                   const unsigned short* __restrict__ xl,
                                                   unsigned short* __restrict__ ef, int M) {
    __shared__ unsigned short bucket[IDS * CAP];   // 4KB
    __shared__ int cl[IDS];
    int cb = blockIdx.x >> 4;            // coarse bin
    int sr = blockIdx.x & (SUB - 1);     // sub-range within bin
    int idBase = (cb << RSB) + (sr << 5);
    if (threadIdx.x < IDS) cl[threadIdx.x] = 0;
    __syncthreads();
    int n = min(binCnt[cb], CAPB);
    const unsigned int* src = binData + (size_t)cb * CAPB;
    for (int i0 = (int)threadIdx.x << 2; i0 < n; i0 += 2048) {
        if (i0 + 4 <= n) {
            uint4 e4 = *(const uint4*)(src + i0);
#define SCAN1(E) { int lid = (int)((E) >> 16) - idBase;                        \
                   if ((unsigned)lid < IDS) {                                  \
                       int r = atomicAdd(&cl[lid], 1);                         \
                       bucket[(lid << 6) + min(r, CAP - 1)] =                  \
                           (unsigned short)((E) & 0xFFFFu); } }
            SCAN1(e4.x) SCAN1(e4.y) SCAN1(e4.z) SCAN1(e4.w)
        } else {
            for (int i = i0; i < n; ++i) { unsigned int e1 = src[i]; SCAN1(e1) }
        }
    }
    __syncthreads();
    int wid = threadIdx.x >> 6, lane = threadIdx.x & 63;
    int half = lane >> 5, hl = lane & 31;
    for (int li = wid; li < IDS; li += 8) {
        int gid = idBase + li;
        if (gid >= M) break;
        int deg = cl[li];
        int dl = min(deg, CAP);
        const unsigned short* col = bucket + (li << 6);
        float4 acc = {0.f, 0.f, 0.f, 0.f};
        int npair = dl >> 1;
        int j = 0;
#define ROW(MID) { uint2 u = *(const uint2*)(xl + (size_t)(MID) * CH + 4 * hl); \
                   acc.x += bflo(u.x); acc.y += bfhi(u.x);                      \
                   acc.z += bflo(u.y); acc.w += bfhi(u.y); }
        for (; j + 4 <= npair; j += 4) {
            int m0 = col[2 * j + half];
            int m1 = col[2 * j + 2 + half];
            int m2 = col[2 * j + 4 + half];
            int m3 = col[2 * j + 6 + half];
            ROW(m0) ROW(m1) ROW(m2) ROW(m3)
        }
        for (; j < npair; ++j) { int m0 = col[2 * j + half]; ROW(m0) }
        if ((dl & 1) && half == 0) { int m0 = col[dl - 1]; ROW(m0) }
#undef ROW
        acc.x += __shfl_xor(acc.x, 32, 64);
        acc.y += __shfl_xor(acc.y, 32, 64);
        acc.z += __shfl_xor(acc.z, 32, 64);
        acc.w += __shfl_xor(acc.w, 32, 64);
        if (half == 0) {
            float binv = deg > 0 ? 1.0f / (float)deg : 0.0f;
            uint2 o;
            o.x = pack2bf(acc.x * binv, acc.y * binv);
            o.y = pack2bf(acc.z * binv, acc.w * binv);
            *(uint2*)(ef + (size_t)gid * CH + 4 * hl) = o;
        }
    }
}

// ---------------------------------------------------------------------------
// Kernel 3: node agg — same half-wave pair structure for the N direction.
//   out[v,:] = (1/sum_{e at v} w[e]) * sum_{e at v} ef_bf[e,:] + bias
// ---------------------------------------------------------------------------
__global__ __launch_bounds__(512, 8) void node_agg(const int* __restrict__ binCnt,
                                                   const unsigned int* __restrict__ binData,
                                                   const unsigned short* __restrict__ ef,
                                                   const float* __restrict__ w,
                                                   const float* __restrict__ bias,
                                                   float* __restrict__ out, int N) {
    __shared__ unsigned short bucket[IDS * CAP];
    __shared__ int cl[IDS];
    int cb = blockIdx.x >> 4;
    int sr = blockIdx.x & (SUB - 1);
    int idBase = (cb << RSB) + (sr << 5);
    if (threadIdx.x < IDS) cl[threadIdx.x] = 0;
    __syncthreads();
    int n = min(binCnt[cb], CAPB);
    const unsigned int* src = binData + (size_t)cb * CAPB;
    for (int i0 = (int)threadIdx.x << 2; i0 < n; i0 += 2048) {
        if (i0 + 4 <= n) {
            uint4 e4 = *(const uint4*)(src + i0);
            SCAN1(e4.x) SCAN1(e4.y) SCAN1(e4.z) SCAN1(e4.w)
        } else {
            for (int i = i0; i < n; ++i) { unsigned int e1 = src[i]; SCAN1(e1) }
        }
    }
#undef SCAN1
    __syncthreads();
    int wid = threadIdx.x >> 6, lane = threadIdx.x & 63;
    int half = lane >> 5, hl = lane & 31;
    for (int li = wid; li < IDS; li += 8) {
        int gid = idBase + li;
        if (gid >= N) break;
        int deg = cl[li];
        int dl = min(deg, CAP);
        const unsigned short* col = bucket + (li << 6);
        float4 acc = {0.f, 0.f, 0.f, 0.f};
        float ds = 0.f;
        int npair = dl >> 1;
        int j = 0;
#define ROW(MID) { uint2 u = *(const uint2*)(ef + (size_t)(MID) * CH + 4 * hl); \
                   ds += w[MID];                                                \
                   acc.x += bflo(u.x); acc.y += bfhi(u.x);                      \
                   acc.z += bflo(u.y); acc.w += bfhi(u.y); }
        for (; j + 4 <= npair; j += 4) {
            int m0 = col[2 * j + half];
            int m1 = col[2 * j + 2 + half];
            int m2 = col[2 * j + 4 + half];
            int m3 = col[2 * j + 6 + half];
            ROW(m0) ROW(m1) ROW(m2) ROW(m3)
        }
        for (; j < npair; ++j) { int m0 = col[2 * j + half]; ROW(m0) }
        if ((dl & 1) && half == 0) { int m0 = col[dl - 1]; ROW(m0) }
#undef ROW
        acc.x += __shfl_xor(acc.x, 32, 64);
        acc.y += __shfl_xor(acc.y, 32, 64);
        acc.z += __shfl_xor(acc.z, 32, 64);
        acc.w += __shfl_xor(acc.w, 32, 64);
        ds    += __shfl_xor(ds,    32, 64);
        if (half == 0) {
            float dinv = ds > 0.f ? 1.0f / ds : 0.0f;
            float4 bi = *(const float4*)(bias + 4 * hl);
            float4 o;
            o.x = acc.x * dinv + bi.x;
            o.y = acc.y * dinv + bi.y;
            o.z = acc.z * dinv + bi.z;
            o.w = acc.w * dinv + bi.w;
            *(float4*)(out + (size_t)gid * CH + 4 * hl) = o;
        }
    }
}

extern "C" void kernel_launch(void* const* d_in, const int* in_sizes, int n_in,
                              void* d_out, int out_size, void* d_ws, size_t ws_size,
                              hipStream_t stream) {
    const float* x      = (const float*)d_in[0];
    const int*   hei    = (const int*)d_in[1];
    const float* attn_w = (const float*)d_in[2];
    const float* attn_b = (const float*)d_in[3];
    const float* lin_w  = (const float*)d_in[4];
    const float* bias   = (const float*)d_in[5];
    float* out = (float*)d_out;

    const int N   = in_sizes[0] / CH;   // 50000 (== M here)
    const int nnz = in_sizes[1] / 2;    // 800000
    const int* nidx = hei;              // row 0: node ids
    const int* eidx = hei + nnz;        // row 1: hyperedge ids

    // workspace layout (~21.2MB):
    //   ef      : N*CH ushorts (12.8MB)
    //   w       : N floats (0.2MB)
    //   binData : 2*nbd*CAPB uints (8.03MB)
    //   binCnt  : 2*nbd ints
    unsigned short* efbf = (unsigned short*)d_ws;
    float*          w    = (float*)(efbf + (size_t)N * CH);
    unsigned int*   binData = (unsigned int*)(w + N);
    int nbd = (N + RS - 1) >> RSB;         // 98 bins per direction
    int*            binCnt  = (int*)(binData + (size_t)2 * nbd * CAPB);

    unsigned short* xlbf = (unsigned short*)out;   // bf16 xl in d_out (dead after edge_agg)

    hipMemsetAsync(binCnt, 0, (size_t)2 * nbd * sizeof(int), stream);

    int SB = (nnz + PB - 1) / PB;          // 391 binning blocks
    int nStrips = N / 16;                  // 3125
    int GB = (nStrips + 3) / 4;            // 782 gemm blocks
    fused_main<<<SB + GB, 256, 0, stream>>>(x, attn_w, attn_b, lin_w, xlbf, w,
                                            nStrips, nidx, eidx, binCnt, binData,
                                            nnz, nbd, SB);

    edge_agg<<<nbd * SUB, 512, 0, stream>>>(binCnt, binData, xlbf, efbf, N);
    node_agg<<<nbd * SUB, 512, 0, stream>>>(binCnt + nbd,
                                            binData + (size_t)nbd * CAPB,
                                            efbf, w, bias, out, N);
}